// Round 5
// baseline (144.256 us; speedup 1.0000x reference)
//
#include <hip/hip_runtime.h>
#include <math.h>

#define DD 160
#define HH 192
#define WW 160
#define TW 16          // tile width  (per 64-lane block)
#define TH 4           // tile height
#define TD 16          // slices per block
#define HW (HH * WW)
#define NVOX (DD * HW)
#define HTW 18         // halo cols
#define HTH 6          // halo rows
#define LSTR 20        // LDS row stride (banks: <=3-way aliasing, mostly 2)
#define HALO (HTH * HTW)   // 108
#define NSLOT 64       // reduction scratch slots (128B apart)

// atan via odd minimax poly on [0,1] + rcp range reduction; max err ~1e-5 rad
__device__ __forceinline__ float atan_fast(float r) {
    float ar = fabsf(r);
    float inv = __builtin_amdgcn_rcpf(ar);
    bool big = ar > 1.0f;
    float x = big ? inv : ar;
    float x2 = x * x;
    float p = fmaf(x2, fmaf(x2, fmaf(x2, fmaf(x2, fmaf(x2,
              -0.0117212f, 0.05265332f), -0.11643287f), 0.19354346f),
              -0.33262347f), 0.99997726f);
    p *= x;
    float res = big ? (1.57079632679489662f - p) : p;
    return copysignf(res, r);
}

// Single-wave workgroup: __syncthreads() compiles to waitcnt only (barrier
// elided for flat-workgroup-size <= 64) — the whole d-pipeline is wave-local.
__global__ __launch_bounds__(64) void demons_ori_kernel(
    const float* __restrict__ Mv, const float* __restrict__ Sv,
    const float* __restrict__ flow, float* __restrict__ ws)
{
    __shared__ float buf[2][2][HTH * LSTR];   // [parity][field][h*LSTR+w]

    const int tid = threadIdx.x;
    const int tw = tid & 15;
    const int th = tid >> 4;
    const int w0 = blockIdx.x * TW;
    const int h0 = blockIdx.y * TH;
    const int d0 = blockIdx.z * TD;

    // slice-invariant staging slots: slot0 = tid, slot1 = tid+64 (if <108)
    const bool has1 = (tid < HALO - 64);
    int idx0, gb0, idx1 = 0, gb1 = 0;
    bool ok0, ok1 = false;
    {
        int i = tid;
        int hh = i / HTW, ww = i - HTW * hh;
        int gh = h0 + hh - 1, gw = w0 + ww - 1;
        idx0 = hh * LSTR + ww;
        ok0 = (gh >= 0 && gh < HH && gw >= 0 && gw < WW);
        gb0 = gh * WW + gw;
        if (has1) {
            i = tid + 64;
            hh = i / HTW; ww = i - HTW * hh;
            gh = h0 + hh - 1; gw = w0 + ww - 1;
            idx1 = hh * LSTR + ww;
            ok1 = (gh >= 0 && gh < HH && gw >= 0 && gw < WW);
            gb1 = gh * WW + gw;
        }
    }

    // prefetch registers — named scalars only (round-3 lesson: arrays passed
    // to lambdas demote to scratch)
    float pS0 = 0.f, pM0 = 0.f, pS1 = 0.f, pM1 = 0.f;

    auto issue = [&](int d) {
        const bool din = (d >= 0) && (d < DD);
        const size_t base = (size_t)d * HW;
        pS0 = (din && ok0) ? Sv[base + gb0] : 0.f;
        pM0 = (din && ok0) ? Mv[base + gb0] : 0.f;
        pS1 = (din && ok1) ? Sv[base + gb1] : 0.f;
        pM1 = (din && ok1) ? Mv[base + gb1] : 0.f;
    };
    auto commit = [&](int d) {
        float* __restrict__ bS = &buf[d & 1][0][0];
        float* __restrict__ bM = &buf[d & 1][1][0];
        bS[idx0] = pS0;
        bM[idx0] = pM0;
        if (has1) { bS[idx1] = pS1; bM[idx1] = pM1; }
    };

    const int rb = th * LSTR + tw;   // center voxel at (th+1, tw+1)
    // separable in-plane partials: pq[f] = {Px, Py, B, center}
    auto partials = [&](int par, float pq[2][4]) {
        #pragma unroll
        for (int f = 0; f < 2; ++f) {
            const float* __restrict__ b = &buf[par][f][0];
            const float* r0 = b + rb;
            const float* r1 = r0 + LSTR;
            const float* r2 = r1 + LSTR;
            float v00 = r0[0], v01 = r0[1], v02 = r0[2];
            float v10 = r1[0], v11 = r1[1], v12 = r1[2];
            float v20 = r2[0], v21 = r2[1], v22 = r2[2];
            pq[f][0] = (v02 + 2.f * v12 + v22) - (v00 + 2.f * v10 + v20);
            pq[f][1] = (v20 + 2.f * v21 + v22) - (v00 + 2.f * v01 + v02);
            pq[f][2] = (v00 + v01 + v02) + 2.f * (v10 + v11 + v12)
                     + (v20 + v21 + v22);
            pq[f][3] = v11;
        }
    };

    float Pm[2][4], P0[2][4], Pp[2][4];

    // ---- warmup pipeline ----
    issue(d0 - 1);
    commit(d0 - 1);          // only exposed vmcnt wait of the whole block
    issue(d0);
    __syncthreads();
    partials((d0 - 1) & 1, Pm);
    commit(d0);
    issue(d0 + 1);
    __syncthreads();
    partials(d0 & 1, P0);

    const size_t voff0 = (size_t)(h0 + th) * WW + (w0 + tw);
    float fFx = flow[(size_t)d0 * HW + voff0];
    float fFy = flow[(size_t)NVOX + (size_t)d0 * HW + voff0];
    float fFz = flow[2 * (size_t)NVOX + (size_t)d0 * HW + voff0];

    float lsum = 0.f;

    #pragma unroll 4
    for (int dd = 0; dd < TD; ++dd) {
        const int d = d0 + dd;
        commit(d + 1);       // vmcnt wait for loads issued a full stage ago
        float nFx = 0.f, nFy = 0.f, nFz = 0.f;
        if (dd < TD - 1) {
            issue(d + 2);    // in flight across this whole stage
            size_t foff = (size_t)(d + 1) * HW + voff0;
            nFx = flow[foff];
            nFy = flow[(size_t)NVOX + foff];
            nFz = flow[2 * (size_t)NVOX + foff];
        }
        __syncthreads();     // wave-local: waitcnt only, no s_barrier
        partials((d + 1) & 1, Pp);

        float idf = P0[1][3] - P0[0][3];
        float i2 = idf * idf + 1e-10f;
        float gxS = Pm[0][0] + P0[0][0] + Pp[0][0];
        float gyS = Pm[0][1] + P0[0][1] + Pp[0][1];
        float gzS = Pp[0][2] - Pm[0][2];
        float gxM = Pm[1][0] + P0[1][0] + Pp[1][0];
        float gyM = Pm[1][1] + P0[1][1] + Pp[1][1];
        float gzM = Pp[1][2] - Pm[1][2];
        float denS = gxS * gxS + gyS * gyS + gzS * gzS + i2;
        float denM = gxM * gxM + gyM * gyM + gzM * gzM + i2;
        float rS = __builtin_amdgcn_rcpf(denS);
        float rM = __builtin_amdgcn_rcpf(denM);
        float Ux = idf * (gxS * rS + gxM * rM);
        float Uy = idf * (gyS * rS + gyM * rM);
        float Uz = idf * (gzS * rS + gzM * rM);
        float rz = __builtin_amdgcn_rcpf(Uz + 1e-10f);
        float dxz = atan_fast(Ux * rz);
        float dyz = atan_fast(Uy * rz);

        float rf = __builtin_amdgcn_rcpf(fFz + 1e-10f);
        float fxz = atan_fast(fFx * rf);
        float fyz = atan_fast(fFy * rf);

        float e1 = fxz - dxz;
        float e2 = fyz - dyz;
        lsum += e1 * e1 + e2 * e2;

        #pragma unroll
        for (int f = 0; f < 2; ++f)
            #pragma unroll
            for (int q = 0; q < 4; ++q) {
                Pm[f][q] = P0[f][q];
                P0[f][q] = Pp[f][q];
            }
        fFx = nFx; fFy = nFy; fFz = nFz;
    }

    // wave shuffle reduce -> scatter atomics over 64 cache-line-spaced slots
    #pragma unroll
    for (int o = 32; o > 0; o >>= 1)
        lsum += __shfl_down(lsum, o, 64);
    if (tid == 0) {
        int bid = (blockIdx.z * gridDim.y + blockIdx.y) * gridDim.x + blockIdx.x;
        atomicAdd(ws + (bid & (NSLOT - 1)) * 32, lsum);
    }
}

__global__ __launch_bounds__(64) void reduce_kernel(
    const float* __restrict__ ws, float* __restrict__ out)
{
    float v = ws[threadIdx.x * 32];
    #pragma unroll
    for (int o = 32; o > 0; o >>= 1)
        v += __shfl_down(v, o, 64);
    if (threadIdx.x == 0)
        out[0] = v * (1.0f / (float)NVOX);
}

extern "C" void kernel_launch(void* const* d_in, const int* in_sizes, int n_in,
                              void* d_out, int out_size, void* d_ws, size_t ws_size,
                              hipStream_t stream) {
    const float* Mv   = (const float*)d_in[0];
    const float* Sv   = (const float*)d_in[1];
    const float* flow = (const float*)d_in[2];
    float* out = (float*)d_out;
    float* ws  = (float*)d_ws;

    hipMemsetAsync(ws, 0, NSLOT * 32 * sizeof(float), stream);

    dim3 grid(WW / TW, HH / TH, DD / TD);   // 10 x 48 x 10 = 4800 one-wave blocks
    demons_ori_kernel<<<grid, dim3(64), 0, stream>>>(Mv, Sv, flow, ws);
    reduce_kernel<<<dim3(1), dim3(64), 0, stream>>>(ws, out);
}